// Round 16
// baseline (212.503 us; speedup 1.0000x reference)
//
#include <hip/hip_runtime.h>

// Causal self-attention, S=4096, E=D=1024, fp32 in/out.
// R26 (= R25 with the k_red2 coverage bug fixed). R25 failed correctness:
//   the V-reduce used 1024 blocks = 256K float4 but V = 1M float4 -> 3/4 of
//   Vb stale (absmax 162). Fix: k_red2 grid 4096+4096=8192, V branch spans
//   the full 1M float4. All else identical to R25:
//   - y-core 32KB: Ah/Al in LDS (BK=64), Bh/Bl (Mth/Mtl, L2-resident)
//     per-lane global->reg. Bit-identical y.
//   - V split-K=2 fp32 partials -> yv grid 1024 @32KB = 4/CU all-resident.
//   - M split-K 8->4 (raw-fp32 core in k_mix).
//   Layout: Mp[40,56) yp[40,72) Vp[72,104) Wvth@104 Mth@106 Mtl@108.
//   RULE (R14): no device-scope fences in hot kernels on gfx950.

typedef unsigned short u16;
typedef unsigned int   u32;
typedef __bf16 bf16x8 __attribute__((ext_vector_type(8)));
typedef float  f32x16 __attribute__((ext_vector_type(16)));
typedef u16    u16x8  __attribute__((ext_vector_type(8)));

#define SLEN 4096
#define EDIM 1024
#define CCAP 32

__device__ __forceinline__ u16 f2bf(float x) {
    union { float f; u32 u; } c; c.f = x;
    return (u16)((c.u + 0x7FFFu + ((c.u >> 16) & 1u)) >> 16);
}
__device__ __forceinline__ float bf2f(u16 h) {
    union { u32 u; float f; } c; c.u = ((u32)h) << 16;
    return c.f;
}

__device__ __forceinline__ void gll16(const void* g, u16* l) {
    __builtin_amdgcn_global_load_lds(
        (const __attribute__((address_space(1))) void*)g,
        (__attribute__((address_space(3))) void*)l, 16, 0, 0);
}

__device__ __forceinline__ void split_f4(const float* __restrict__ in,
                                         u16* __restrict__ hi,
                                         u16* __restrict__ lo, int i) {
    const float4 v = reinterpret_cast<const float4*>(in)[i];
    u16 h0 = f2bf(v.x), h1 = f2bf(v.y), h2 = f2bf(v.z), h3 = f2bf(v.w);
    reinterpret_cast<ushort4*>(hi)[i] = make_ushort4(h0, h1, h2, h3);
    reinterpret_cast<ushort4*>(lo)[i] =
        make_ushort4(f2bf(v.x - bf2f(h0)), f2bf(v.y - bf2f(h1)),
                     f2bf(v.z - bf2f(h2)), f2bf(v.w - bf2f(h3)));
}

// ---- GEMM core from RAW FP32 operands: 128x128 tile, BK=32, 32KB LDS ------
// Stages fp32 A/B tiles via gll16; splits to hi/lo bf16 in-register at
// consume (same f2bf formulas as prep) -> bit-identical to TERMS=3 path.
// Row = 32 floats = 8 chunks of 16B; phys chunk p of row r holds logical
// p^(r&7); read-side XOR = l31&7.
__device__ __forceinline__ void gemm_core_f32(
    u16* smem_u16,
    const float* __restrict__ A, const float* __restrict__ B,
    int K, int kbeg, int kend, int rowA0, int rowB0,
    int tid, f32x16 (&acc)[2][2]) {
    const float* smem = (const float*)smem_u16;
    const int lane = tid & 63, wv = tid >> 6;
    const int wm = (wv >> 1) * 64, wn = (wv & 1) * 64;
    const int l31 = lane & 31, lh = lane >> 5;
    const int swz = l31 & 7;

    const float* pA = A + (size_t)rowA0 * K;
    const float* pB = B + (size_t)rowB0 * K;

    for (int k0 = kbeg; k0 < kend; k0 += 32) {
#pragma unroll
        for (int i = 0; i < 4; i++) {
            int c = i * 256 + tid;
            int m = c >> 3;
            int kb = (c & 7) ^ (m & 7);  // source pre-swizzle (3-bit)
            gll16(pA + (size_t)m * K + (k0 + kb * 4), smem_u16 + c * 8);
            gll16(pB + (size_t)m * K + (k0 + kb * 4), smem_u16 + 8192 + c * 8);
        }
        __syncthreads();
#pragma unroll
        for (int ks = 0; ks < 2; ks++) {
            const int l0 = ks * 4 + lh * 2;       // logical chunk (even)
            const int p0 = ((l0 ^ swz) << 2);     // float offset, chunk 0
            const int p1 = (((l0 + 1) ^ swz) << 2);
            bf16x8 a[2], al[2], b[2], bl[2];
#pragma unroll
            for (int i = 0; i < 2; i++) {
                {
                    const float* base = smem + (wm + i * 32 + l31) * 32;
                    float4 f0 = *(const float4*)(base + p0);
                    float4 f1 = *(const float4*)(base + p1);
                    float f[8] = {f0.x, f0.y, f0.z, f0.w,
                                  f1.x, f1.y, f1.z, f1.w};
                    u16x8 hh, ll;
#pragma unroll
                    for (int e = 0; e < 8; e++) {
                        u16 h = f2bf(f[e]);
                        hh[e] = h;
                        ll[e] = f2bf(f[e] - bf2f(h));
                    }
                    a[i]  = __builtin_bit_cast(bf16x8, hh);
                    al[i] = __builtin_bit_cast(bf16x8, ll);
                }
                {
                    const float* base = smem + 4096 + (wn + i * 32 + l31) * 32;
                    float4 f0 = *(const float4*)(base + p0);
                    float4 f1 = *(const float4*)(base + p1);
                    float f[8] = {f0.x, f0.y, f0.z, f0.w,
                                  f1.x, f1.y, f1.z, f1.w};
                    u16x8 hh, ll;
#pragma unroll
                    for (int e = 0; e < 8; e++) {
                        u16 h = f2bf(f[e]);
                        hh[e] = h;
                        ll[e] = f2bf(f[e] - bf2f(h));
                    }
                    b[i]  = __builtin_bit_cast(bf16x8, hh);
                    bl[i] = __builtin_bit_cast(bf16x8, ll);
                }
            }
#pragma unroll
            for (int mi = 0; mi < 2; mi++)
#pragma unroll
                for (int ni = 0; ni < 2; ni++) {
                    acc[mi][ni] = __builtin_amdgcn_mfma_f32_32x32x16_bf16(a[mi], b[ni], acc[mi][ni], 0, 0, 0);
                    acc[mi][ni] = __builtin_amdgcn_mfma_f32_32x32x16_bf16(a[mi], bl[ni], acc[mi][ni], 0, 0, 0);
                    acc[mi][ni] = __builtin_amdgcn_mfma_f32_32x32x16_bf16(al[mi], b[ni], acc[mi][ni], 0, 0, 0);
                }
        }
        __syncthreads();
    }
}

// -------- GEMM core BK=64: 128x128 tile, TERMS=1, single-buffer 32KB -------
// LDS: A [0,8192) u16, B [8192,16384); row r = 64 u16 (128B), 8 slots of 8.
// Phys slot p of row r holds K-chunk p^(r&7); read swz = l31&7.
__device__ __forceinline__ void gemm_core_k64(
    u16* smem,
    const u16* __restrict__ A, const u16* __restrict__ B,
    int K, int kbeg, int kend, int rowA0, int rowB0,
    int tid, f32x16 (&acc)[2][2]) {
    const int lane = tid & 63, wv = tid >> 6;
    const int wm = (wv >> 1) * 64, wn = (wv & 1) * 64;
    const int l31 = lane & 31, lh = lane >> 5;
    const int swz = l31 & 7;

    const u16* sA = A + (size_t)rowA0 * K;
    const u16* sB = B + (size_t)rowB0 * K;

    for (int k0 = kbeg; k0 < kend; k0 += 64) {
#pragma unroll
        for (int i = 0; i < 4; i++) {
            int c = i * 256 + tid;
            int m = c >> 3;
            int kb = (c & 7) ^ (m & 7);  // source pre-swizzle (3-bit)
            gll16(sA + (size_t)m * K + (k0 + kb * 8), smem + c * 8);
            gll16(sB + (size_t)m * K + (k0 + kb * 8), smem + 8192 + c * 8);
        }
        __syncthreads();
#pragma unroll
        for (int ks = 0; ks < 4; ks++) {
            const int so = ((((ks << 1) | lh) ^ swz) << 3);
            bf16x8 a[2], b[2];
#pragma unroll
            for (int i = 0; i < 2; i++) {
                a[i] = *(const bf16x8*)(smem + (wm + i * 32 + l31) * 64 + so);
                b[i] = *(const bf16x8*)(smem + 8192 + (wn + i * 32 + l31) * 64 + so);
            }
#pragma unroll
            for (int mi = 0; mi < 2; mi++)
#pragma unroll
                for (int ni = 0; ni < 2; ni++)
                    acc[mi][ni] = __builtin_amdgcn_mfma_f32_32x32x16_bf16(a[mi], b[ni], acc[mi][ni], 0, 0, 0);
        }
        __syncthreads();
    }
}

// ---- GEMM core BK=64 TERMS=3, 32KB: Ah/Al in LDS, Bh AND Bl in regs -------
// Bh/Bl fragments read per-lane global->reg (both L2-resident, 2MB each).
// Same MFMA K-order as the BK=32 TERMS=3 path -> bit-identical numerics.
__device__ __forceinline__ void gemm_core_k64_breg(
    u16* smem,
    const u16* __restrict__ Ah, const u16* __restrict__ Al,
    const u16* __restrict__ Bh, const u16* __restrict__ Bl,
    int K, int kbeg, int kend, int rowA0, int rowB0,
    int tid, f32x16 (&acc)[2][2]) {
    const int lane = tid & 63, wv = tid >> 6;
    const int wm = (wv >> 1) * 64, wn = (wv & 1) * 64;
    const int l31 = lane & 31, lh = lane >> 5;
    const int swz = l31 & 7;

    const u16* sA0 = Ah + (size_t)rowA0 * K;
    const u16* sA1 = Al + (size_t)rowA0 * K;
    const u16* pBh = Bh + (size_t)rowB0 * K;
    const u16* pBl = Bl + (size_t)rowB0 * K;

    for (int k0 = kbeg; k0 < kend; k0 += 64) {
#pragma unroll
        for (int i = 0; i < 4; i++) {
            int c = i * 256 + tid;
            int m = c >> 3;
            int kb = (c & 7) ^ (m & 7);  // source pre-swizzle (3-bit)
            gll16(sA0 + (size_t)m * K + (k0 + kb * 8), smem + c * 8);
            gll16(sA1 + (size_t)m * K + (k0 + kb * 8), smem + 8192 + c * 8);
        }
        __syncthreads();
#pragma unroll
        for (int ks = 0; ks < 4; ks++) {
            const int lsl = (ks << 1) | lh;        // logical slot 0..7
            const int so = (lsl ^ swz) << 3;
            bf16x8 a[2], al2[2], b[2], bl2[2];
#pragma unroll
            for (int i = 0; i < 2; i++) {
                a[i]   = *(const bf16x8*)(smem + (wm + i * 32 + l31) * 64 + so);
                al2[i] = *(const bf16x8*)(smem + 8192 + (wm + i * 32 + l31) * 64 + so);
                b[i]   = *(const bf16x8*)(pBh + (size_t)(wn + i * 32 + l31) * K
                                          + k0 + lsl * 8);
                bl2[i] = *(const bf16x8*)(pBl + (size_t)(wn + i * 32 + l31) * K
                                          + k0 + lsl * 8);
            }
#pragma unroll
            for (int mi = 0; mi < 2; mi++)
#pragma unroll
                for (int ni = 0; ni < 2; ni++) {
                    acc[mi][ni] = __builtin_amdgcn_mfma_f32_32x32x16_bf16(a[mi], b[ni], acc[mi][ni], 0, 0, 0);
                    acc[mi][ni] = __builtin_amdgcn_mfma_f32_32x32x16_bf16(a[mi], bl2[ni], acc[mi][ni], 0, 0, 0);
                    acc[mi][ni] = __builtin_amdgcn_mfma_f32_32x32x16_bf16(al2[mi], b[ni], acc[mi][ni], 0, 0, 0);
                }
        }
        __syncthreads();
    }
}

// C/D 32x32 layout: col = lane&31, row = (r&3) + 8*(r>>2) + 4*(lane>>5)
#define EPILOGUE_32(BODY)                                                    \
    {                                                                        \
    const int lane = threadIdx.x & 63, wv = threadIdx.x >> 6;                \
    const int wm = (wv >> 1) * 64, wn = (wv & 1) * 64;                       \
    const int l31 = lane & 31, lh4 = (lane >> 5) * 4;                        \
    _Pragma("unroll")                                                        \
    for (int mi = 0; mi < 2; mi++)                                           \
        _Pragma("unroll")                                                    \
        for (int ni = 0; ni < 2; ni++)                                       \
            _Pragma("unroll")                                                \
            for (int r = 0; r < 16; r++) {                                   \
                int row = wm + mi * 32 + (r & 3) + 8 * (r >> 2) + lh4;       \
                int col = wn + ni * 32 + l31;                                \
                float val = acc[mi][ni][r];                                  \
                BODY                                                         \
            }                                                                \
    }

// ---- mixed: b<256 = Mt partials from RAW fp32 Wk/Wq (splitK=4);
// ----        b<4352 = x split; else Wv transpose. Independent halves ------
__global__ __launch_bounds__(256) void k_mix(
    const float* __restrict__ x, const float* __restrict__ Wv,
    const float* __restrict__ Wk, const float* __restrict__ Wq,
    u16* __restrict__ xh, u16* __restrict__ xl,
    u16* __restrict__ Wvth, float* __restrict__ Mp) {
    __shared__ u16 smem[16384];  // 32KB; prep blocks alias/ignore
    const int b = blockIdx.x, tid = threadIdx.x;
    if (b < 256) {
        const int bz = b >> 6, by = (b >> 3) & 7, bx = b & 7;
        f32x16 acc[2][2] = {};
        const int rowA0 = by * 128, rowB0 = bx * 128;
        const int kbeg = bz * 256;
        float* Mz = Mp + (size_t)bz * EDIM * EDIM;
        gemm_core_f32(smem, Wk, Wq, EDIM, kbeg, kbeg + 256,
                      rowA0, rowB0, tid, acc);
        EPILOGUE_32({ Mz[(size_t)(rowA0 + row) * EDIM + (rowB0 + col)] = val; })
    } else if (b < 4352) {
        split_f4(x, xh, xl, (b - 256) * 256 + tid);
    } else {
        float (*tile)[33] = reinterpret_cast<float(*)[33]>(smem);
        int t = b - 4352;
        int tx = tid & 31, ty = tid >> 5;
        int c0 = (t & 31) * 32, r0 = (t >> 5) * 32;
#pragma unroll
        for (int r = 0; r < 4; r++)
            tile[ty + r * 8][tx] = Wv[(size_t)(r0 + ty + r * 8) * EDIM + (c0 + tx)];
        __syncthreads();
#pragma unroll
        for (int r = 0; r < 4; r++)
            Wvth[(size_t)(c0 + ty + r * 8) * EDIM + (r0 + tx)] =
                f2bf(tile[tx][ty + r * 8]);
    }
}

// ---- reduce nsrc fp32 partials (stride4 float4 apart) + split hi/lo -------
__global__ __launch_bounds__(256) void k_redsplit(
    const float* __restrict__ base, int stride4, int nsrc,
    u16* __restrict__ hi, u16* __restrict__ lo, int n4) {
    int i = blockIdx.x * 256 + threadIdx.x;
    if (i >= n4) return;
    float4 v = reinterpret_cast<const float4*>(base)[i];
    for (int s = 1; s < nsrc; s++) {
        float4 a = reinterpret_cast<const float4*>(base)[(size_t)s * stride4 + i];
        v.x += a.x; v.y += a.y; v.z += a.z; v.w += a.w;
    }
    u16 h0 = f2bf(v.x), h1 = f2bf(v.y), h2 = f2bf(v.z), h3 = f2bf(v.w);
    reinterpret_cast<ushort4*>(hi)[i] = make_ushort4(h0, h1, h2, h3);
    reinterpret_cast<ushort4*>(lo)[i] =
        make_ushort4(f2bf(v.x - bf2f(h0)), f2bf(v.y - bf2f(h1)),
                     f2bf(v.z - bf2f(h2)), f2bf(v.w - bf2f(h3)));
}

// ---- reduce y (hi/lo out) AND V (bf16 out) in one launch (8192 blocks) ----
// y: blocks [0,4096) cover 1M float4; V: blocks [4096,8192) cover 1M float4.
__global__ __launch_bounds__(256) void k_red2(
    const float* __restrict__ yp, const float* __restrict__ Vp,
    u16* __restrict__ yh, u16* __restrict__ yl, u16* __restrict__ Vb) {
    const int b = blockIdx.x, tid = threadIdx.x;
    const int stride4 = (SLEN * EDIM) / 4;
    if (b < 4096) {
        int i = b * 256 + tid;
        float4 v = reinterpret_cast<const float4*>(yp)[i];
        float4 a = reinterpret_cast<const float4*>(yp)[(size_t)stride4 + i];
        v.x += a.x; v.y += a.y; v.z += a.z; v.w += a.w;
        u16 h0 = f2bf(v.x), h1 = f2bf(v.y), h2 = f2bf(v.z), h3 = f2bf(v.w);
        reinterpret_cast<ushort4*>(yh)[i] = make_ushort4(h0, h1, h2, h3);
        reinterpret_cast<ushort4*>(yl)[i] =
            make_ushort4(f2bf(v.x - bf2f(h0)), f2bf(v.y - bf2f(h1)),
                         f2bf(v.z - bf2f(h2)), f2bf(v.w - bf2f(h3)));
    } else {
        int i = (b - 4096) * 256 + tid;  // full 1M float4 of V
        float4 v = reinterpret_cast<const float4*>(Vp)[i];
        float4 a = reinterpret_cast<const float4*>(Vp)[(size_t)stride4 + i];
        reinterpret_cast<ushort4*>(Vb)[i] =
            make_ushort4(f2bf(v.x + a.x), f2bf(v.y + a.y),
                         f2bf(v.z + a.z), f2bf(v.w + a.w));
    }
}

// ---- merged: b<512: y splitK=2 (32KB breg); else V splitK=2 (BK=64) -------
// grid 1024 @ 32KB -> 4 blocks/CU, ALL resident. XCD: 64 y + 64 V per XCD.
__global__ __launch_bounds__(256) void k_gemm_yv(
    const u16* __restrict__ xh, const u16* __restrict__ xl,
    const u16* __restrict__ Mth, const u16* __restrict__ Mtl,
    const u16* __restrict__ Wvth,
    float* __restrict__ yp, float* __restrict__ Vp) {
    __shared__ u16 smem[16384];  // 32KB
    f32x16 acc[2][2] = {};
    const int b0 = blockIdx.x;
    const int xcd = b0 & 7, j = b0 >> 3;
    const int b = (j < 64) ? (xcd * 64 + j) : (512 + xcd * 64 + (j - 64));
    if (b < 512) {
        int s = b >> 8, r = b & 255;
        int tm = r >> 3, tn = r & 7;
        gemm_core_k64_breg(smem, xh, xl, Mth, Mtl, EDIM, s * 512, s * 512 + 512,
                           tm * 128, tn * 128, threadIdx.x, acc);
        float* Py = yp + (size_t)s * SLEN * EDIM;
        EPILOGUE_32({
            Py[(size_t)(tm * 128 + row) * EDIM + (tn * 128 + col)] = val;
        })
    } else {
        int b2 = b - 512;
        int s2 = b2 >> 8, r2 = b2 & 255;
        int tm = r2 >> 3, tn = r2 & 7;  // V[m][n] = sum_k x[m][k] Wv[k][n]
        gemm_core_k64(smem, xh, Wvth, EDIM, s2 * 512, s2 * 512 + 512,
                      tm * 128, tn * 128, threadIdx.x, acc);
        float* Pv = Vp + (size_t)s2 * SLEN * EDIM;
        EPILOGUE_32({
            Pv[(size_t)(tm * 128 + row) * EDIM + (tn * 128 + col)] = val;
        })
    }
}

// ---- APPROX S = yh*xh^T /32, tri tiles, split-K=2 halves, BK=64 -----------
__global__ __launch_bounds__(256) void k_sa(
    const u16* __restrict__ yh, const u16* __restrict__ xh,
    u16* __restrict__ Sh0, u16* __restrict__ Sh1) {
    __shared__ u16 smem[16384];
    int b0 = blockIdx.x;
    int b = (b0 & 7) * 132 + (b0 >> 3);  // bijective (1056 % 8 == 0)
    int half = (b >= 528) ? 1 : 0;
    int t = b - half * 528;
    int ti = (int)((sqrtf(8.0f * (float)t + 1.0f) - 1.0f) * 0.5f);
    while ((ti + 1) * (ti + 2) / 2 <= t) ti++;
    while (ti * (ti + 1) / 2 > t) ti--;
    int tm = ti, tn = t - ti * (ti + 1) / 2;
    f32x16 acc[2][2] = {};
    gemm_core_k64(smem, yh, xh, EDIM, half * 512, half * 512 + 512,
                  tm * 128, tn * 128, threadIdx.x, acc);
    u16* Cb = (half ? Sh1 : Sh0) + (size_t)t * 16384;
    EPILOGUE_32({ Cb[row * 128 + col] = f2bf(val * 0.03125f); })
}

// ---- finish: per row -- approx max, candidates (max-64), exact fp32 dots,
// ---- softmax over candidates, V gather. One block per row. ----------------
__global__ __launch_bounds__(256) void k_finish(
    const u16* __restrict__ Sh0, const u16* __restrict__ Sh1,
    const u16* __restrict__ yh, const u16* __restrict__ yl,
    const u16* __restrict__ xh, const u16* __restrict__ xl,
    const u16* __restrict__ Vb, float* __restrict__ out) {
    __shared__ u16 syh[EDIM], syl[EDIM];  // 4KB y row (hi/lo)
    __shared__ float red[4];
    __shared__ int cidx[CCAP];
    __shared__ float cs[CCAP];
    __shared__ int cnt;

    const int row = blockIdx.x, tid = threadIdx.x;
    const int lane = tid & 63, wid = tid >> 6;
    const int n = row + 1;
    const int tm = row >> 7, rl = row & 127;
    const size_t base = (size_t)(tm * (tm + 1) / 2) * 16384 + rl * 128;
    const u16* s0 = Sh0 + base;
    const u16* s1 = Sh1 + base;

    // y row to LDS (256 thr x ushort4 = 1024)
    ((ushort4*)syh)[tid] = ((const ushort4*)(yh + (size_t)row * EDIM))[tid];
    ((ushort4*)syl)[tid] = ((const ushort4*)(yl + (size_t)row * EDIM))[tid];
    if (tid == 0) cnt = 0;

    // approx logits in registers: each thread owns 8 consecutive j per iter
    float vals[16];
    float m = -3.0e38f;
#pragma unroll
    for (int it = 0; it < 2; it++) {
        int j0 = (it * 256 + tid) * 8;
        size_t idx = (size_t)(j0 >> 7) * 16384 + (j0 & 127);
        u16x8 v0 = *(const u16x8*)(s0 + idx);
        u16x8 v1 = *(const u16x8*)(s1 + idx);
#pragma unroll
        for (int e = 0; e < 8; e++) {
            int j = j0 + e;
            float v = (j < n) ? (bf2f(v0[e]) + bf2f(v1[e])) : -3.0e38f;
            vals[it * 8 + e] = v;
            m = fmaxf(m, v);
        }
    }
#pragma unroll
    for (int o = 32; o; o >>= 1) m = fmaxf(m, __shfl_xor(m, o));
    if (lane == 0) red[wid] = m;
    __syncthreads();
    m = fmaxf(fmaxf(red[0], red[1]), fmaxf(red[2], red[3]));
    __syncthreads();

    // candidate scan: approx s > max - 64 captures all exact s > max_ex - 17
    float thr = m - 64.0f;
#pragma unroll
    for (int it = 0; it < 2; it++) {
        int j0 = (it * 256 + tid) * 8;
#pragma unroll
        for (int e = 0; e < 8; e++) {
            if (vals[it * 8 + e] > thr) {  // implies j < n (masked to -3e38)
                int pos = atomicAdd(&cnt, 1);
                if (pos < CCAP) cidx[pos] = j0 + e;
            }
        }
    }
    __syncthreads();
    int C = min(cnt, CCAP);

    // exact logits: one wave per candidate, fp32 dot (yh+yl)*(xh+xl)
    for (int k = wid; k < C; k += 4) {
        int j = cidx[k];
        const u16* xhj = xh + (size_t)j * EDIM;
        const u16* xlj = xl + (size_t)j * EDIM;
        const int e0 = lane * 16;
        u16x8 xv0 = *(const u16x8*)(xhj + e0);
        u16x8 xv1 = *(const u16x8*)(xhj + e0 + 8);
        u16x8 xw0 = *(const u16x8*)(xlj + e0);
        u16x8 xw1 = *(const u16x8*)(xlj + e0 + 8);
        u16x8 yv0 = *(const u16x8*)(syh + e0);
        u16x8 yv1 = *(const u16x8*)(syh + e0 + 8);
        u16x8 yw0 = *(const u16x8*)(syl + e0);
        u16x8 yw1 = *(const u16x8*)(syl + e0 + 8);
        float a = 0.f;
#pragma unroll
        for (int e = 0; e < 8; e++) {
            a += (bf2f(yv0[e]) + bf2f(yw0[e])) * (bf2f(xv0[e]) + bf2f(xw0[e]));
            a += (bf2f(yv1[e]) + bf2f(yw1[e])) * (bf2f(xv1[e]) + bf2f(xw1[e]));
        }
#pragma unroll
        for (int o = 32; o; o >>= 1) a += __shfl_xor(a, o);
        if (lane == 0) cs[k] = a * 0.03125f;
    }
    __syncthreads();

    // softmax over candidates (redundant per-thread over <=32 entries)
    float me = -3.0e38f;
    for (int k = 0; k < C; k++) me = fmaxf(me, cs[k]);
    float S = 0.f;
    for (int k = 0; k < C; k++) S += __expf(cs[k] - me);
    float invS = 1.0f / S;

    // gather: out[row] = sum_k p_k * V[j_k]; each thread owns 4 cols
    const int d0 = tid * 4;
    float4 o4 = make_float4(0.f, 0.f, 0.f, 0.f);
    for (int k = 0; k < C; k++) {
        float p = __expf(cs[k] - me) * invS;
        ushort4 v = *(const ushort4*)(Vb + (size_t)cidx[k] * EDIM + d0);
        o4.x += p * bf2f(v.x);
        o4.y += p * bf2f(v.y);
        o4.z += p * bf2f(v.z);
        o4.w += p * bf2f(v.w);
    }
    *(float4*)(out + (size_t)row * EDIM + d0) = o4;
}

// ---------------------------------------------------------------------------
extern "C" void kernel_launch(void* const* d_in, const int* in_sizes, int n_in,
                              void* d_out, int out_size, void* d_ws, size_t ws_size,
                              hipStream_t stream) {
    const float* x  = (const float*)d_in[0];
    const float* Wq = (const float*)d_in[1];
    const float* Wk = (const float*)d_in[2];
    const float* Wv = (const float*)d_in[3];
    float* out = (float*)d_out;
    char* ws = (char*)d_ws;
    const size_t MB = 1024 * 1024;

    // persistent
    u16* xh = (u16*)(ws + 0 * MB);     // 8MB, live to finish
    u16* xl = (u16*)(ws + 8 * MB);     // 8MB
    u16* yh = (u16*)(ws + 16 * MB);    // 8MB
    u16* yl = (u16*)(ws + 24 * MB);    // 8MB
    u16* Vb = (u16*)(ws + 32 * MB);    // 8MB row-major bf16
    // scratch timeline:
    //   Mp 4x4MB [40,56)       (k_mix -> dead after k_redsplit)
    //   yp 2x16MB [40,72)      (yv -> dead after k_red2)
    //   Vp 2x16MB [72,104)     (yv -> dead after k_red2)
    //   Sh0 [40,58) Sh1 [58,76) (k_sa -> k_finish; written after yp/Vp dead)
    float* Mp  = (float*)(ws + 40 * MB);
    float* yp  = (float*)(ws + 40 * MB);
    float* Vp  = (float*)(ws + 72 * MB);
    u16* Sh0 = (u16*)(ws + 40 * MB);
    u16* Sh1 = (u16*)(ws + 58 * MB);
    // transients (live through yv; outside [40,104))
    u16* Wvth = (u16*)(ws + 104 * MB);
    u16* Mth  = (u16*)(ws + 106 * MB);
    u16* Mtl  = (u16*)(ws + 108 * MB);    // -110 (ws >= 118 proven R20)

    dim3 b256(256);

    // 1) mixed: Mt partials (splitK=4, raw fp32) + x split + Wv transpose
    k_mix<<<5376, b256, 0, stream>>>(x, Wv, Wk, Wq, xh, xl, Wvth, Mp);

    // 2) reduce 4 + split Mt
    k_redsplit<<<1024, b256, 0, stream>>>(Mp, (EDIM * EDIM) / 4, 4, Mth, Mtl,
                                          (EDIM * EDIM) / 4);

    // 3) y partials (splitK=2, 32KB breg) + V partials (splitK=2)  (1024 blk)
    k_gemm_yv<<<1024, b256, 0, stream>>>(xh, xl, Mth, Mtl, Wvth, yp, Vp);

    // 4) reduce y -> yh/yl and V -> Vb in one launch (8192 blocks)
    k_red2<<<8192, b256, 0, stream>>>(yp, Vp, yh, yl, Vb);

    // 5) approx S = yh*xh^T /32 (bf16, split-K=2 halves, BK=64)
    k_sa<<<1056, b256, 0, stream>>>(yh, xh, Sh0, Sh1);

    // 6) finish: scan + exact re-dot + softmax + gather
    k_finish<<<SLEN, b256, 0, stream>>>(Sh0, Sh1, yh, yl, xh, xl, Vb, out);
}

// Round 17
// 191.718 us; speedup vs baseline: 1.1084x; 1.1084x over previous
//
#include <hip/hip_runtime.h>

// Causal self-attention, S=4096, E=D=1024, fp32 in/out.
// R27: revert R26's yv/V/red changes (4/CU@32KB-breg + V-splitK cost more
//   than residency paid: yv 44.7->57.3, red2 +64MB). Back to R24's PROVEN
//   yv: y splitK=2 via k64t3 (Ah/Al/Bh in 48KB LDS, Bl reg; 3/CU), V
//   full-K k64 -> Vb bf16 direct, separate 4096-blk y-redsplit. KEEP from
//   R26: M splitK=4 (256 gemm blocks x K=256; halves Mp traffic, neutral
//   in R26's regression accounting). Everything else = R24 (best, 191.8).
//   RULE (R14): no device-scope fences in hot kernels on gfx950.

typedef unsigned short u16;
typedef unsigned int   u32;
typedef __bf16 bf16x8 __attribute__((ext_vector_type(8)));
typedef float  f32x16 __attribute__((ext_vector_type(16)));
typedef u16    u16x8  __attribute__((ext_vector_type(8)));

#define SLEN 4096
#define EDIM 1024
#define CCAP 32

__device__ __forceinline__ u16 f2bf(float x) {
    union { float f; u32 u; } c; c.f = x;
    return (u16)((c.u + 0x7FFFu + ((c.u >> 16) & 1u)) >> 16);
}
__device__ __forceinline__ float bf2f(u16 h) {
    union { u32 u; float f; } c; c.u = ((u32)h) << 16;
    return c.f;
}

__device__ __forceinline__ void gll16(const void* g, u16* l) {
    __builtin_amdgcn_global_load_lds(
        (const __attribute__((address_space(1))) void*)g,
        (__attribute__((address_space(3))) void*)l, 16, 0, 0);
}

__device__ __forceinline__ void split_f4(const float* __restrict__ in,
                                         u16* __restrict__ hi,
                                         u16* __restrict__ lo, int i) {
    const float4 v = reinterpret_cast<const float4*>(in)[i];
    u16 h0 = f2bf(v.x), h1 = f2bf(v.y), h2 = f2bf(v.z), h3 = f2bf(v.w);
    reinterpret_cast<ushort4*>(hi)[i] = make_ushort4(h0, h1, h2, h3);
    reinterpret_cast<ushort4*>(lo)[i] =
        make_ushort4(f2bf(v.x - bf2f(h0)), f2bf(v.y - bf2f(h1)),
                     f2bf(v.z - bf2f(h2)), f2bf(v.w - bf2f(h3)));
}

// ---- GEMM core from RAW FP32 operands: 128x128 tile, BK=32, 32KB LDS ------
// Stages fp32 A/B tiles via gll16; splits to hi/lo bf16 in-register at
// consume (same f2bf formulas as prep) -> bit-identical to TERMS=3 path.
// Row = 32 floats = 8 chunks of 16B; phys chunk p of row r holds logical
// p^(r&7); read-side XOR = l31&7.
__device__ __forceinline__ void gemm_core_f32(
    u16* smem_u16,
    const float* __restrict__ A, const float* __restrict__ B,
    int K, int kbeg, int kend, int rowA0, int rowB0,
    int tid, f32x16 (&acc)[2][2]) {
    const float* smem = (const float*)smem_u16;
    const int lane = tid & 63, wv = tid >> 6;
    const int wm = (wv >> 1) * 64, wn = (wv & 1) * 64;
    const int l31 = lane & 31, lh = lane >> 5;
    const int swz = l31 & 7;

    const float* pA = A + (size_t)rowA0 * K;
    const float* pB = B + (size_t)rowB0 * K;

    for (int k0 = kbeg; k0 < kend; k0 += 32) {
#pragma unroll
        for (int i = 0; i < 4; i++) {
            int c = i * 256 + tid;
            int m = c >> 3;
            int kb = (c & 7) ^ (m & 7);  // source pre-swizzle (3-bit)
            gll16(pA + (size_t)m * K + (k0 + kb * 4), smem_u16 + c * 8);
            gll16(pB + (size_t)m * K + (k0 + kb * 4), smem_u16 + 8192 + c * 8);
        }
        __syncthreads();
#pragma unroll
        for (int ks = 0; ks < 2; ks++) {
            const int l0 = ks * 4 + lh * 2;       // logical chunk (even)
            const int p0 = ((l0 ^ swz) << 2);     // float offset, chunk 0
            const int p1 = (((l0 + 1) ^ swz) << 2);
            bf16x8 a[2], al[2], b[2], bl[2];
#pragma unroll
            for (int i = 0; i < 2; i++) {
                {
                    const float* base = smem + (wm + i * 32 + l31) * 32;
                    float4 f0 = *(const float4*)(base + p0);
                    float4 f1 = *(const float4*)(base + p1);
                    float f[8] = {f0.x, f0.y, f0.z, f0.w,
                                  f1.x, f1.y, f1.z, f1.w};
                    u16x8 hh, ll;
#pragma unroll
                    for (int e = 0; e < 8; e++) {
                        u16 h = f2bf(f[e]);
                        hh[e] = h;
                        ll[e] = f2bf(f[e] - bf2f(h));
                    }
                    a[i]  = __builtin_bit_cast(bf16x8, hh);
                    al[i] = __builtin_bit_cast(bf16x8, ll);
                }
                {
                    const float* base = smem + 4096 + (wn + i * 32 + l31) * 32;
                    float4 f0 = *(const float4*)(base + p0);
                    float4 f1 = *(const float4*)(base + p1);
                    float f[8] = {f0.x, f0.y, f0.z, f0.w,
                                  f1.x, f1.y, f1.z, f1.w};
                    u16x8 hh, ll;
#pragma unroll
                    for (int e = 0; e < 8; e++) {
                        u16 h = f2bf(f[e]);
                        hh[e] = h;
                        ll[e] = f2bf(f[e] - bf2f(h));
                    }
                    b[i]  = __builtin_bit_cast(bf16x8, hh);
                    bl[i] = __builtin_bit_cast(bf16x8, ll);
                }
            }
#pragma unroll
            for (int mi = 0; mi < 2; mi++)
#pragma unroll
                for (int ni = 0; ni < 2; ni++) {
                    acc[mi][ni] = __builtin_amdgcn_mfma_f32_32x32x16_bf16(a[mi], b[ni], acc[mi][ni], 0, 0, 0);
                    acc[mi][ni] = __builtin_amdgcn_mfma_f32_32x32x16_bf16(a[mi], bl[ni], acc[mi][ni], 0, 0, 0);
                    acc[mi][ni] = __builtin_amdgcn_mfma_f32_32x32x16_bf16(al[mi], b[ni], acc[mi][ni], 0, 0, 0);
                }
        }
        __syncthreads();
    }
}

// -------- GEMM core BK=64: 128x128 tile, TERMS=1, single-buffer 32KB -------
// LDS: A [0,8192) u16, B [8192,16384); row r = 64 u16 (128B), 8 slots of 8.
// Phys slot p of row r holds K-chunk p^(r&7); read swz = l31&7.
__device__ __forceinline__ void gemm_core_k64(
    u16* smem,
    const u16* __restrict__ A, const u16* __restrict__ B,
    int K, int kbeg, int kend, int rowA0, int rowB0,
    int tid, f32x16 (&acc)[2][2]) {
    const int lane = tid & 63, wv = tid >> 6;
    const int wm = (wv >> 1) * 64, wn = (wv & 1) * 64;
    const int l31 = lane & 31, lh = lane >> 5;
    const int swz = l31 & 7;

    const u16* sA = A + (size_t)rowA0 * K;
    const u16* sB = B + (size_t)rowB0 * K;

    for (int k0 = kbeg; k0 < kend; k0 += 64) {
#pragma unroll
        for (int i = 0; i < 4; i++) {
            int c = i * 256 + tid;
            int m = c >> 3;
            int kb = (c & 7) ^ (m & 7);  // source pre-swizzle (3-bit)
            gll16(sA + (size_t)m * K + (k0 + kb * 8), smem + c * 8);
            gll16(sB + (size_t)m * K + (k0 + kb * 8), smem + 8192 + c * 8);
        }
        __syncthreads();
#pragma unroll
        for (int ks = 0; ks < 4; ks++) {
            const int so = ((((ks << 1) | lh) ^ swz) << 3);
            bf16x8 a[2], b[2];
#pragma unroll
            for (int i = 0; i < 2; i++) {
                a[i] = *(const bf16x8*)(smem + (wm + i * 32 + l31) * 64 + so);
                b[i] = *(const bf16x8*)(smem + 8192 + (wn + i * 32 + l31) * 64 + so);
            }
#pragma unroll
            for (int mi = 0; mi < 2; mi++)
#pragma unroll
                for (int ni = 0; ni < 2; ni++)
                    acc[mi][ni] = __builtin_amdgcn_mfma_f32_32x32x16_bf16(a[mi], b[ni], acc[mi][ni], 0, 0, 0);
        }
        __syncthreads();
    }
}

// ---- GEMM core BK=64 TERMS=3 hybrid: Ah/Al/Bh in LDS (48KB), Bl in regs ---
// Bl fragments read per-lane global->reg (L2-resident Mt). Same MFMA K-order
// as the BK=32 TERMS=3 path -> bit-identical numerics.
__device__ __forceinline__ void gemm_core_k64t3(
    u16* smem,
    const u16* __restrict__ Ah, const u16* __restrict__ Al,
    const u16* __restrict__ Bh, const u16* __restrict__ Bl,
    int K, int kbeg, int kend, int rowA0, int rowB0,
    int tid, f32x16 (&acc)[2][2]) {
    const int lane = tid & 63, wv = tid >> 6;
    const int wm = (wv >> 1) * 64, wn = (wv & 1) * 64;
    const int l31 = lane & 31, lh = lane >> 5;
    const int swz = l31 & 7;

    const u16* sA0 = Ah + (size_t)rowA0 * K;
    const u16* sA1 = Al + (size_t)rowA0 * K;
    const u16* sB0 = Bh + (size_t)rowB0 * K;
    const u16* pBl = Bl + (size_t)rowB0 * K;

    for (int k0 = kbeg; k0 < kend; k0 += 64) {
#pragma unroll
        for (int i = 0; i < 4; i++) {
            int c = i * 256 + tid;
            int m = c >> 3;
            int kb = (c & 7) ^ (m & 7);  // source pre-swizzle (3-bit)
            gll16(sA0 + (size_t)m * K + (k0 + kb * 8), smem + c * 8);
            gll16(sA1 + (size_t)m * K + (k0 + kb * 8), smem + 8192 + c * 8);
            gll16(sB0 + (size_t)m * K + (k0 + kb * 8), smem + 16384 + c * 8);
        }
        __syncthreads();
#pragma unroll
        for (int ks = 0; ks < 4; ks++) {
            const int lsl = (ks << 1) | lh;        // logical slot 0..7
            const int so = (lsl ^ swz) << 3;
            bf16x8 a[2], al2[2], b[2], bl2[2];
#pragma unroll
            for (int i = 0; i < 2; i++) {
                a[i]   = *(const bf16x8*)(smem + (wm + i * 32 + l31) * 64 + so);
                al2[i] = *(const bf16x8*)(smem + 8192 + (wm + i * 32 + l31) * 64 + so);
                b[i]   = *(const bf16x8*)(smem + 16384 + (wn + i * 32 + l31) * 64 + so);
                bl2[i] = *(const bf16x8*)(pBl + (size_t)(wn + i * 32 + l31) * K
                                          + k0 + lsl * 8);
            }
#pragma unroll
            for (int mi = 0; mi < 2; mi++)
#pragma unroll
                for (int ni = 0; ni < 2; ni++) {
                    acc[mi][ni] = __builtin_amdgcn_mfma_f32_32x32x16_bf16(a[mi], b[ni], acc[mi][ni], 0, 0, 0);
                    acc[mi][ni] = __builtin_amdgcn_mfma_f32_32x32x16_bf16(a[mi], bl2[ni], acc[mi][ni], 0, 0, 0);
                    acc[mi][ni] = __builtin_amdgcn_mfma_f32_32x32x16_bf16(al2[mi], b[ni], acc[mi][ni], 0, 0, 0);
                }
        }
        __syncthreads();
    }
}

// C/D 32x32 layout: col = lane&31, row = (r&3) + 8*(r>>2) + 4*(lane>>5)
#define EPILOGUE_32(BODY)                                                    \
    {                                                                        \
    const int lane = threadIdx.x & 63, wv = threadIdx.x >> 6;                \
    const int wm = (wv >> 1) * 64, wn = (wv & 1) * 64;                       \
    const int l31 = lane & 31, lh4 = (lane >> 5) * 4;                        \
    _Pragma("unroll")                                                        \
    for (int mi = 0; mi < 2; mi++)                                           \
        _Pragma("unroll")                                                    \
        for (int ni = 0; ni < 2; ni++)                                       \
            _Pragma("unroll")                                                \
            for (int r = 0; r < 16; r++) {                                   \
                int row = wm + mi * 32 + (r & 3) + 8 * (r >> 2) + lh4;       \
                int col = wn + ni * 32 + l31;                                \
                float val = acc[mi][ni][r];                                  \
                BODY                                                         \
            }                                                                \
    }

// ---- mixed: b<256 = Mt partials from RAW fp32 Wk/Wq (splitK=4);
// ----        b<4352 = x split; else Wv transpose. Independent halves ------
__global__ __launch_bounds__(256) void k_mix(
    const float* __restrict__ x, const float* __restrict__ Wv,
    const float* __restrict__ Wk, const float* __restrict__ Wq,
    u16* __restrict__ xh, u16* __restrict__ xl,
    u16* __restrict__ Wvth, float* __restrict__ Mp) {
    __shared__ u16 smem[16384];  // 32KB; prep blocks alias/ignore
    const int b = blockIdx.x, tid = threadIdx.x;
    if (b < 256) {
        const int bz = b >> 6, by = (b >> 3) & 7, bx = b & 7;
        f32x16 acc[2][2] = {};
        const int rowA0 = by * 128, rowB0 = bx * 128;
        const int kbeg = bz * 256;
        float* Mz = Mp + (size_t)bz * EDIM * EDIM;
        gemm_core_f32(smem, Wk, Wq, EDIM, kbeg, kbeg + 256,
                      rowA0, rowB0, tid, acc);
        EPILOGUE_32({ Mz[(size_t)(rowA0 + row) * EDIM + (rowB0 + col)] = val; })
    } else if (b < 4352) {
        split_f4(x, xh, xl, (b - 256) * 256 + tid);
    } else {
        float (*tile)[33] = reinterpret_cast<float(*)[33]>(smem);
        int t = b - 4352;
        int tx = tid & 31, ty = tid >> 5;
        int c0 = (t & 31) * 32, r0 = (t >> 5) * 32;
#pragma unroll
        for (int r = 0; r < 4; r++)
            tile[ty + r * 8][tx] = Wv[(size_t)(r0 + ty + r * 8) * EDIM + (c0 + tx)];
        __syncthreads();
#pragma unroll
        for (int r = 0; r < 4; r++)
            Wvth[(size_t)(c0 + ty + r * 8) * EDIM + (r0 + tx)] =
                f2bf(tile[tx][ty + r * 8]);
    }
}

// ---- reduce nsrc fp32 partials (stride4 float4 apart) + split hi/lo -------
__global__ __launch_bounds__(256) void k_redsplit(
    const float* __restrict__ base, int stride4, int nsrc,
    u16* __restrict__ hi, u16* __restrict__ lo, int n4) {
    int i = blockIdx.x * 256 + threadIdx.x;
    if (i >= n4) return;
    float4 v = reinterpret_cast<const float4*>(base)[i];
    for (int s = 1; s < nsrc; s++) {
        float4 a = reinterpret_cast<const float4*>(base)[(size_t)s * stride4 + i];
        v.x += a.x; v.y += a.y; v.z += a.z; v.w += a.w;
    }
    u16 h0 = f2bf(v.x), h1 = f2bf(v.y), h2 = f2bf(v.z), h3 = f2bf(v.w);
    reinterpret_cast<ushort4*>(hi)[i] = make_ushort4(h0, h1, h2, h3);
    reinterpret_cast<ushort4*>(lo)[i] =
        make_ushort4(f2bf(v.x - bf2f(h0)), f2bf(v.y - bf2f(h1)),
                     f2bf(v.z - bf2f(h2)), f2bf(v.w - bf2f(h3)));
}

// ---- merged: b<512: y split-K=2 (BK=64 hybrid); else V = x*Wv (BK=64) -----
// grid 768 = 3 blocks/CU (48KB LDS). XCD-balanced: 64 y + 32 V per XCD.
__global__ __launch_bounds__(256) void k_gemm_yv(
    const u16* __restrict__ xh, const u16* __restrict__ xl,
    const u16* __restrict__ Mth, const u16* __restrict__ Mtl,
    const u16* __restrict__ Wvth,
    float* __restrict__ yp, u16* __restrict__ Vb) {
    __shared__ u16 smem[24576];  // 48KB (y hybrid); V uses first 32KB
    f32x16 acc[2][2] = {};
    const int b0 = blockIdx.x;
    const int xcd = b0 & 7, j = b0 >> 3;
    const int b = (j < 64) ? (xcd * 64 + j) : (512 + xcd * 32 + (j - 64));
    if (b < 512) {
        int s = b >> 8, r = b & 255;
        int tm = r >> 3, tn = r & 7;
        gemm_core_k64t3(smem, xh, xl, Mth, Mtl, EDIM, s * 512, s * 512 + 512,
                        tm * 128, tn * 128, threadIdx.x, acc);
        float* Py = yp + (size_t)s * SLEN * EDIM;
        EPILOGUE_32({
            Py[(size_t)(tm * 128 + row) * EDIM + (tn * 128 + col)] = val;
        })
    } else {
        int b2 = b - 512;
        int tm = b2 >> 3, tn = b2 & 7;  // V[m][n] = sum_k x[m][k] Wv[k][n]
        gemm_core_k64(smem, xh, Wvth, EDIM, 0, EDIM,
                      tm * 128, tn * 128, threadIdx.x, acc);
        EPILOGUE_32({
            Vb[(size_t)(tm * 128 + row) * EDIM + (tn * 128 + col)] = f2bf(val);
        })
    }
}

// ---- APPROX S = yh*xh^T /32, tri tiles, split-K=2 halves, BK=64 -----------
__global__ __launch_bounds__(256) void k_sa(
    const u16* __restrict__ yh, const u16* __restrict__ xh,
    u16* __restrict__ Sh0, u16* __restrict__ Sh1) {
    __shared__ u16 smem[16384];
    int b0 = blockIdx.x;
    int b = (b0 & 7) * 132 + (b0 >> 3);  // bijective (1056 % 8 == 0)
    int half = (b >= 528) ? 1 : 0;
    int t = b - half * 528;
    int ti = (int)((sqrtf(8.0f * (float)t + 1.0f) - 1.0f) * 0.5f);
    while ((ti + 1) * (ti + 2) / 2 <= t) ti++;
    while (ti * (ti + 1) / 2 > t) ti--;
    int tm = ti, tn = t - ti * (ti + 1) / 2;
    f32x16 acc[2][2] = {};
    gemm_core_k64(smem, yh, xh, EDIM, half * 512, half * 512 + 512,
                  tm * 128, tn * 128, threadIdx.x, acc);
    u16* Cb = (half ? Sh1 : Sh0) + (size_t)t * 16384;
    EPILOGUE_32({ Cb[row * 128 + col] = f2bf(val * 0.03125f); })
}

// ---- finish: per row -- approx max, candidates (max-64), exact fp32 dots,
// ---- softmax over candidates, V gather. One block per row. ----------------
__global__ __launch_bounds__(256) void k_finish(
    const u16* __restrict__ Sh0, const u16* __restrict__ Sh1,
    const u16* __restrict__ yh, const u16* __restrict__ yl,
    const u16* __restrict__ xh, const u16* __restrict__ xl,
    const u16* __restrict__ Vb, float* __restrict__ out) {
    __shared__ u16 syh[EDIM], syl[EDIM];  // 4KB y row (hi/lo)
    __shared__ float red[4];
    __shared__ int cidx[CCAP];
    __shared__ float cs[CCAP];
    __shared__ int cnt;

    const int row = blockIdx.x, tid = threadIdx.x;
    const int lane = tid & 63, wid = tid >> 6;
    const int n = row + 1;
    const int tm = row >> 7, rl = row & 127;
    const size_t base = (size_t)(tm * (tm + 1) / 2) * 16384 + rl * 128;
    const u16* s0 = Sh0 + base;
    const u16* s1 = Sh1 + base;

    // y row to LDS (256 thr x ushort4 = 1024)
    ((ushort4*)syh)[tid] = ((const ushort4*)(yh + (size_t)row * EDIM))[tid];
    ((ushort4*)syl)[tid] = ((const ushort4*)(yl + (size_t)row * EDIM))[tid];
    if (tid == 0) cnt = 0;

    // approx logits in registers: each thread owns 8 consecutive j per iter
    float vals[16];
    float m = -3.0e38f;
#pragma unroll
    for (int it = 0; it < 2; it++) {
        int j0 = (it * 256 + tid) * 8;
        size_t idx = (size_t)(j0 >> 7) * 16384 + (j0 & 127);
        u16x8 v0 = *(const u16x8*)(s0 + idx);
        u16x8 v1 = *(const u16x8*)(s1 + idx);
#pragma unroll
        for (int e = 0; e < 8; e++) {
            int j = j0 + e;
            float v = (j < n) ? (bf2f(v0[e]) + bf2f(v1[e])) : -3.0e38f;
            vals[it * 8 + e] = v;
            m = fmaxf(m, v);
        }
    }
#pragma unroll
    for (int o = 32; o; o >>= 1) m = fmaxf(m, __shfl_xor(m, o));
    if (lane == 0) red[wid] = m;
    __syncthreads();
    m = fmaxf(fmaxf(red[0], red[1]), fmaxf(red[2], red[3]));
    __syncthreads();

    // candidate scan: approx s > max - 64 captures all exact s > max_ex - 17
    float thr = m - 64.0f;
#pragma unroll
    for (int it = 0; it < 2; it++) {
        int j0 = (it * 256 + tid) * 8;
#pragma unroll
        for (int e = 0; e < 8; e++) {
            if (vals[it * 8 + e] > thr) {  // implies j < n (masked to -3e38)
                int pos = atomicAdd(&cnt, 1);
                if (pos < CCAP) cidx[pos] = j0 + e;
            }
        }
    }
    __syncthreads();
    int C = min(cnt, CCAP);

    // exact logits: one wave per candidate, fp32 dot (yh+yl)*(xh+xl)
    for (int k = wid; k < C; k += 4) {
        int j = cidx[k];
        const u16* xhj = xh + (size_t)j * EDIM;
        const u16* xlj = xl + (size_t)j * EDIM;
        const int e0 = lane * 16;
        u16x8 xv0 = *(const u16x8*)(xhj + e0);
        u16x8 xv1 = *(const u16x8*)(xhj + e0 + 8);
        u16x8 xw0 = *(const u16x8*)(xlj + e0);
        u16x8 xw1 = *(const u16x8*)(xlj + e0 + 8);
        u16x8 yv0 = *(const u16x8*)(syh + e0);
        u16x8 yv1 = *(const u16x8*)(syh + e0 + 8);
        u16x8 yw0 = *(const u16x8*)(syl + e0);
        u16x8 yw1 = *(const u16x8*)(syl + e0 + 8);
        float a = 0.f;
#pragma unroll
        for (int e = 0; e < 8; e++) {
            a += (bf2f(yv0[e]) + bf2f(yw0[e])) * (bf2f(xv0[e]) + bf2f(xw0[e]));
            a += (bf2f(yv1[e]) + bf2f(yw1[e])) * (bf2f(xv1[e]) + bf2f(xw1[e]));
        }
#pragma unroll
        for (int o = 32; o; o >>= 1) a += __shfl_xor(a, o);
        if (lane == 0) cs[k] = a * 0.03125f;
    }
    __syncthreads();

    // softmax over candidates (redundant per-thread over <=32 entries)
    float me = -3.0e38f;
    for (int k = 0; k < C; k++) me = fmaxf(me, cs[k]);
    float S = 0.f;
    for (int k = 0; k < C; k++) S += __expf(cs[k] - me);
    float invS = 1.0f / S;

    // gather: out[row] = sum_k p_k * V[j_k]; each thread owns 4 cols
    const int d0 = tid * 4;
    float4 o4 = make_float4(0.f, 0.f, 0.f, 0.f);
    for (int k = 0; k < C; k++) {
        float p = __expf(cs[k] - me) * invS;
        ushort4 v = *(const ushort4*)(Vb + (size_t)cidx[k] * EDIM + d0);
        o4.x += p * bf2f(v.x);
        o4.y += p * bf2f(v.y);
        o4.z += p * bf2f(v.z);
        o4.w += p * bf2f(v.w);
    }
    *(float4*)(out + (size_t)row * EDIM + d0) = o4;
}

// ---------------------------------------------------------------------------
extern "C" void kernel_launch(void* const* d_in, const int* in_sizes, int n_in,
                              void* d_out, int out_size, void* d_ws, size_t ws_size,
                              hipStream_t stream) {
    const float* x  = (const float*)d_in[0];
    const float* Wq = (const float*)d_in[1];
    const float* Wk = (const float*)d_in[2];
    const float* Wv = (const float*)d_in[3];
    float* out = (float*)d_out;
    char* ws = (char*)d_ws;
    const size_t MB = 1024 * 1024;

    // persistent
    u16* xh = (u16*)(ws + 0 * MB);     // 8MB, live to finish
    u16* xl = (u16*)(ws + 8 * MB);     // 8MB
    u16* yh = (u16*)(ws + 16 * MB);    // 8MB
    u16* yl = (u16*)(ws + 24 * MB);    // 8MB
    u16* Vb = (u16*)(ws + 32 * MB);    // 8MB row-major bf16
    // scratch timeline:
    //   Mp 4x4MB [40,56)       (k_mix -> dead after k_redsplit#1)
    //   yp 2x16MB [40,72)      (yv -> dead after k_redsplit#2)
    //   Sh0 [40,58) Sh1 [58,76) (k_sa -> k_finish; written after yp dead)
    float* Mp  = (float*)(ws + 40 * MB);
    float* yp  = (float*)(ws + 40 * MB);
    u16* Sh0 = (u16*)(ws + 40 * MB);
    u16* Sh1 = (u16*)(ws + 58 * MB);
    // transients (live through yv; outside [40,76))
    u16* Wvth = (u16*)(ws + 104 * MB);
    u16* Mth  = (u16*)(ws + 106 * MB);
    u16* Mtl  = (u16*)(ws + 108 * MB);    // -110 (ws >= 110 proven R26)

    dim3 b256(256);

    // 1) mixed: Mt partials (splitK=4, raw fp32) + x split + Wv transpose
    k_mix<<<5376, b256, 0, stream>>>(x, Wv, Wk, Wq, xh, xl, Wvth, Mp);

    // 2) reduce 4 + split Mt
    k_redsplit<<<1024, b256, 0, stream>>>(Mp, (EDIM * EDIM) / 4, 4, Mth, Mtl,
                                          (EDIM * EDIM) / 4);

    // 3) y partials (split-K=2, BK=64 hybrid) + V = x*Wv   (768 = 3/CU)
    k_gemm_yv<<<768, b256, 0, stream>>>(xh, xl, Mth, Mtl, Wvth, yp, Vb);

    // 4) reduce 2 + split y -> yh/yl
    k_redsplit<<<4096, b256, 0, stream>>>(yp, (SLEN * EDIM) / 4, 2, yh, yl,
                                          (SLEN * EDIM) / 4);

    // 5) approx S = yh*xh^T /32 (bf16, split-K=2 halves, BK=64)
    k_sa<<<1056, b256, 0, stream>>>(yh, xh, Sh0, Sh1);

    // 6) finish: scan + exact re-dot + softmax + gather
    k_finish<<<SLEN, b256, 0, stream>>>(Sh0, Sh1, yh, yl, xh, xl, Vb, out);
}